// Round 13
// baseline (200602.258 us; speedup 1.0000x reference)
//
#include <hip/hip_runtime.h>
#include <math.h>

#define B_ 32
#define T_ 512
#define D_ 1024
#define H_ 1024
#define L_ 4
#define NTICK (T_ + L_ - 1)    // 515

typedef unsigned long long u64;

// Cross-XCD state access: agent-scope relaxed atomics (sc1) hit the MALL
// coherence point directly. No fences anywhere -> XCD L2s never invalidated.
__device__ __forceinline__ float4 load_state4(const float* p) {
    u64 a = __hip_atomic_load((const u64*)p,       __ATOMIC_RELAXED, __HIP_MEMORY_SCOPE_AGENT);
    u64 b = __hip_atomic_load((const u64*)(p + 2), __ATOMIC_RELAXED, __HIP_MEMORY_SCOPE_AGENT);
    float4 v;
    v.x = __uint_as_float((unsigned)(a & 0xffffffffu));
    v.y = __uint_as_float((unsigned)(a >> 32));
    v.z = __uint_as_float((unsigned)(b & 0xffffffffu));
    v.w = __uint_as_float((unsigned)(b >> 32));
    return v;
}

// Relaxed spin + s_sleep throttle; short timeout + always-release => no hang.
__device__ __forceinline__ void waitCount(const unsigned int* p, unsigned int target) {
    int c = 0;
    while (__hip_atomic_load(p, __ATOMIC_RELAXED, __HIP_MEMORY_SCOPE_AGENT) < target) {
        __builtin_amdgcn_s_sleep(16);
        if (++c > 20000) return;   // ~4 ms/tick cap
    }
}

// One K-tile of 256: read this tile's 8 weights from LDS (stable region),
// barrier -> stage 32x256 into LDS -> barrier -> 32 b-rows x
// {2 ds_read_b128 + 8 FMA}. TILE is a literal (rule-#20: compile-time paths).
#define TILE_BODY(TILE)                                                         \
    do {                                                                        \
        constexpr int kof = (TILE & 3) << 8;                                    \
        const float*  src = (TILE < 4) ? xsrc : hrow;                           \
        const size_t  str = (TILE < 4) ? xstr : (size_t)H_;                     \
        const bool useAtomic = (TILE >= 4) || (layer != 0);                     \
        const int widx = (jj << 11) + ((((TILE) << 8) + kb) ^ sw);              \
        const float4 wA = *(const float4*)&Wlds[widx];                          \
        const float4 wB = *(const float4*)&Wlds[widx + 4];                      \
        __syncthreads();                                                        \
        _Pragma("unroll")                                                       \
        for (int s4 = 0; s4 < 4; ++s4) {                                        \
            const int r = srow + (s4 << 3);                                     \
            const float* sp = &src[(size_t)r * str + kof + scol];               \
            float4 v = useAtomic ? load_state4(sp) : *(const float4*)sp;        \
            *(float4*)&xs[r][scol] = v;                                         \
        }                                                                       \
        __syncthreads();                                                        \
        _Pragma("unroll")                                                       \
        for (int b = 0; b < 32; ++b) {                                          \
            const float4 a0 = *(const float4*)&xs[b][kb];                       \
            const float4 a1 = *(const float4*)&xs[b][kb + 4];                   \
            acc[b] += a0.x * wA.x + a0.y * wA.y + a0.z * wA.z + a0.w * wA.w     \
                    + a1.x * wB.x + a1.y * wB.y + a1.z * wB.z + a1.w * wB.w;    \
        }                                                                       \
    } while (0)

// K-reduction phase P (literal): threads dump acc[8P..8P+7] into padded LDS,
// 128 threads sum 32 kslot-partials each, apply tanh/tau, sc1-store h.
#define REDUCE_PHASE(P)                                                         \
    do {                                                                        \
        __syncthreads();                                                        \
        _Pragma("unroll")                                                       \
        for (int q = 0; q < 8; ++q)                                             \
            red[tid * 9 + q] = acc[((P) << 3) + q];                             \
        __syncthreads();                                                        \
        if (tid < 128) {                                                        \
            const int q = tid >> 4;                                             \
            const int b = ((P) << 3) + q;                                       \
            float s = 0.f;                                                      \
            _Pragma("unroll")                                                   \
            for (int ks = 0; ks < 32; ++ks)                                     \
                s += red[(ks * 16 + jj) * 9 + q];                               \
            const float dx   = tanhf(s + bias);                                 \
            const float hold = __hip_atomic_load(&hrow[(size_t)b * H_ + jg],    \
                                __ATOMIC_RELAXED, __HIP_MEMORY_SCOPE_AGENT);    \
            const float hn   = hold + (dx - hold) / tv;                         \
            __hip_atomic_store(&wl[(size_t)b * H_ + jg], hn,                    \
                               __ATOMIC_RELAXED, __HIP_MEMORY_SCOPE_AGENT);     \
        }                                                                       \
    } while (0)

// Persistent kernel: 256 blocks (1/CU), 512 threads = 16 jj x 32 kslot.
// R13 change (single variable vs R9): the block's 128 KB weight slice lives in
// LDS (loaded once), replacing the per-tick global weight stream that R9's
// counters showed was the binding term (36.6 MB/tick past L2 = the tick time).
// No VGPR pressure added -> sidesteps the 128-VGPR spill wall (R10/R12).
// LDS: 128 KB weights + 32 KB staging (reduce aliases staging) = 160 KB.
__global__ __launch_bounds__(512, 1) void lnn_persist(
    const float* __restrict__ x,      // [B][T][D]
    const float* __restrict__ W_in,   // [L][D][H]
    const float* __restrict__ b_in,   // [L][H]
    const float* __restrict__ W_h,    // [L][H][H]
    const float* __restrict__ b_h,    // [L][H]
    const float* __restrict__ tau,    // [L][H]
    float* __restrict__ buf0,         // [L][B][H] state, tick-parity 0
    float* __restrict__ buf1,         // [L][B][H] state, tick-parity 1
    unsigned int* __restrict__ count) // [NTICK] lockstep counters
{
    const int tid   = threadIdx.x;
    const int layer = blockIdx.x >> 6;
    const int jbase = (blockIdx.x & 63) << 4;
    const int jj    = tid & 15;       // col within slice
    const int kslot = tid >> 4;       // 0..31
    const int jg    = jbase + jj;
    const int kb    = kslot << 3;     // k offset within 256-tile
    const int sw    = (jj & 7) << 3;  // weight-LDS XOR swizzle (bits 3-5 of k)

    __shared__ __align__(16) float smem[40960];         // 163,840 B = 160 KiB
    float* Wlds = smem;                                 // [16][2048] swizzled
    float (*xs)[256] = (float(*)[256])(smem + 32768);   // staging 32 KB
    float* red = smem + 32768;                          // reduce, aliases xs

    const float* Wl_in = W_in + (size_t)layer * D_ * H_;
    const float* Wl_h  = W_h  + (size_t)layer * H_ * H_;

    // ---- one-time: load this block's weight slice into LDS ----
    // Thread (jj,kslot) owns k = tl*256 + kb + i (i 0..7) of column jg, stored
    // contiguously at [jj][(tl*256+kb)^sw] -> 2 ds_write_b128 per tl.
#pragma unroll
    for (int tl = 0; tl < 8; ++tl) {
        const float* wp = ((tl < 4) ? Wl_in : Wl_h) + (size_t)((tl & 3) * 256 + kb) * H_ + jg;
        float4 a, b;
        a.x = wp[0];
        a.y = wp[(size_t)H_];
        a.z = wp[(size_t)2 * H_];
        a.w = wp[(size_t)3 * H_];
        b.x = wp[(size_t)4 * H_];
        b.y = wp[(size_t)5 * H_];
        b.z = wp[(size_t)6 * H_];
        b.w = wp[(size_t)7 * H_];
        const int widx = (jj << 11) + (((tl << 8) + kb) ^ sw);
        *(float4*)&Wlds[widx]     = a;
        *(float4*)&Wlds[widx + 4] = b;
    }

    const float bias = b_in[layer * H_ + jg] + b_h[layer * H_ + jg];
    const float tv   = tau[layer * H_ + jg];

    for (int tick = 0; tick < NTICK; ++tick) {
        if (tid == 0 && tick > 0)
            waitCount(&count[tick - 1], 256u);
        __syncthreads();   // orders all threads after the wait (and after init)

        const int t = tick - layer;
        if (t >= 0 && t < T_) {
            const float* rb   = (tick & 1) ? buf0 : buf1;   // state at t-1
            float*       wb   = (tick & 1) ? buf1 : buf0;   // state at t
            const float* hrow = rb + (size_t)layer * B_ * H_;

            const float* xsrc; size_t xstr;
            if (layer == 0) { xsrc = x + (size_t)t * D_;                  xstr = (size_t)T_ * D_; }
            else            { xsrc = rb + (size_t)(layer - 1) * B_ * H_;  xstr = H_; }

            float acc[32];
#pragma unroll
            for (int i = 0; i < 32; ++i) acc[i] = 0.f;

            // staging role: e = s4*512 + tid -> row e>>6, float4-col e&63
            const int srow = tid >> 6;
            const int scol = (tid & 63) << 2;

            TILE_BODY(0); TILE_BODY(1); TILE_BODY(2); TILE_BODY(3);
            TILE_BODY(4); TILE_BODY(5); TILE_BODY(6); TILE_BODY(7);

            float* wl = wb + (size_t)layer * B_ * H_;
            REDUCE_PHASE(0); REDUCE_PHASE(1); REDUCE_PHASE(2); REDUCE_PHASE(3);
        }

        // __syncthreads() drains every wave's vmem ops (s_waitcnt vmcnt(0)
        // before s_barrier) -> all sc1 stores at MALL before the release-add.
        __syncthreads();
        if (tid == 0)
            __hip_atomic_fetch_add(&count[tick], 1u,
                                   __ATOMIC_RELEASE, __HIP_MEMORY_SCOPE_AGENT);
    }
}

// out[b][o] = sum_k h3[b][k] * W_out[k][o] + b_out[o]   (validated rounds 0-12)
__global__ __launch_bounds__(256) void lnn_out(
    const float* __restrict__ H3,     // [B][H]
    const float* __restrict__ W_out,  // [H][O]
    const float* __restrict__ b_out,  // [O]
    float* __restrict__ out)          // [B][O]
{
    const int gid = blockIdx.x * 256 + threadIdx.x;  // 64 blocks -> 16384 threads
    const int jj  = gid & 1023;
    const int b2  = gid >> 10;                       // 0..15 -> rows b2, b2+16
    float acc0 = b_out[jj];
    float acc1 = b_out[jj];
    for (int k = 0; k < H_; ++k) {
        const float w = W_out[k * H_ + jj];
        acc0 += H3[b2 * H_ + k]        * w;
        acc1 += H3[(b2 + 16) * H_ + k] * w;
    }
    out[b2 * H_ + jj]        = acc0;
    out[(b2 + 16) * H_ + jj] = acc1;
}

extern "C" void kernel_launch(void* const* d_in, const int* in_sizes, int n_in,
                              void* d_out, int out_size, void* d_ws, size_t ws_size,
                              hipStream_t stream) {
    const float* x     = (const float*)d_in[0];
    const float* W_in  = (const float*)d_in[1];
    const float* b_in  = (const float*)d_in[2];
    const float* W_h   = (const float*)d_in[3];
    const float* b_h   = (const float*)d_in[4];
    const float* tau   = (const float*)d_in[5];
    const float* W_out = (const float*)d_in[6];
    const float* b_out = (const float*)d_in[7];

    const size_t stateElems = (size_t)L_ * B_ * H_;       // 131072 floats
    float* buf0 = (float*)d_ws;
    float* buf1 = buf0 + stateElems;
    unsigned int* count = (unsigned int*)(buf1 + stateElems);

    // zero state + lockstep counters (captured in graph -> reset every replay)
    (void)hipMemsetAsync(d_ws, 0,
                         2 * stateElems * sizeof(float) + NTICK * sizeof(unsigned int), stream);

    lnn_persist<<<256, 512, 0, stream>>>(x, W_in, b_in, W_h, b_h, tau, buf0, buf1, count);

    // h3 at t=511 computed at tick 514 -> write parity 514&1 = 0 -> buf0.
    // Kernel boundary provides coherence for these plain loads.
    const float* H3 = buf0 + 3 * (B_ * H_);
    lnn_out<<<64, 256, 0, stream>>>(H3, W_out, b_out, (float*)d_out);
}

// Round 14
// 87487.335 us; speedup vs baseline: 2.2929x; 2.2929x over previous
//
#include <hip/hip_runtime.h>
#include <math.h>

#define B_ 32
#define T_ 512
#define D_ 1024
#define H_ 1024
#define L_ 4
#define NTICK (T_ + L_ - 1)    // 515
#define RP 17                  // reduce row pad (floats), proven R0/R7/R9
#define SMEM_FLOATS (512 * RP) // 34816 B; aliases staging tile xs[32][256]
#define PACK_PER_BLK 32768     // 16 cols x 2048 k floats = 128 KB per block

typedef unsigned long long u64;

// Cross-XCD state access: agent-scope relaxed atomics (sc1) hit the MALL
// coherence point directly. No fences anywhere -> XCD L2s never invalidated.
__device__ __forceinline__ float4 load_state4(const float* p) {
    u64 a = __hip_atomic_load((const u64*)p,       __ATOMIC_RELAXED, __HIP_MEMORY_SCOPE_AGENT);
    u64 b = __hip_atomic_load((const u64*)(p + 2), __ATOMIC_RELAXED, __HIP_MEMORY_SCOPE_AGENT);
    float4 v;
    v.x = __uint_as_float((unsigned)(a & 0xffffffffu));
    v.y = __uint_as_float((unsigned)(a >> 32));
    v.z = __uint_as_float((unsigned)(b & 0xffffffffu));
    v.w = __uint_as_float((unsigned)(b >> 32));
    return v;
}

// Relaxed spin + s_sleep throttle; short timeout + always-release => no hang.
__device__ __forceinline__ void waitCount(const unsigned int* p, unsigned int target) {
    int c = 0;
    while (__hip_atomic_load(p, __ATOMIC_RELAXED, __HIP_MEMORY_SCOPE_AGENT) < target) {
        __builtin_amdgcn_s_sleep(16);
        if (++c > 20000) return;   // ~4 ms/tick cap
    }
}

// One K-tile of 256 (R9 structure): weight loads -> barrier -> stage 32x256
// into LDS -> barrier -> 32 b-rows x {2 ds_read_b128 + 8 FMA}.
// R14 single variable: PACKED=true reads the thread's 8 weights as TWO
// CONTIGUOUS float4 from the repacked per-block blob (R9 counters showed the
// strided-dword weight stream moved at 1.0 TB/s = request-rate-bound = the
// entire 36.9 us tick). Register footprint identical (wc[8]).
#define TILE_BODY(TILE)                                                         \
    do {                                                                        \
        constexpr int kof = (TILE & 3) << 8;                                    \
        const float*  src = (TILE < 4) ? xsrc : hrow;                           \
        const size_t  str = (TILE < 4) ? xstr : (size_t)H_;                     \
        const bool useAtomic = (TILE >= 4) || (layer != 0);                     \
        float wc[8];                                                            \
        if constexpr (PACKED) {                                                 \
            const float4 wA = *(const float4*)&wbase[((TILE) << 8) + kb];       \
            const float4 wB = *(const float4*)&wbase[((TILE) << 8) + kb + 4];   \
            wc[0] = wA.x; wc[1] = wA.y; wc[2] = wA.z; wc[3] = wA.w;             \
            wc[4] = wB.x; wc[5] = wB.y; wc[6] = wB.z; wc[7] = wB.w;             \
        } else {                                                                \
            const float* wp = ((TILE < 4) ? Wl_in : Wl_h)                       \
                            + (size_t)(kof + kb) * H_ + jg;                     \
            _Pragma("unroll")                                                   \
            for (int i = 0; i < 8; ++i) wc[i] = wp[(size_t)i * H_];             \
        }                                                                       \
        __syncthreads();                                                        \
        _Pragma("unroll")                                                       \
        for (int s4 = 0; s4 < 4; ++s4) {                                        \
            const int r = srow + (s4 << 3);                                     \
            const float* sp = &src[(size_t)r * str + kof + scol];               \
            float4 v = useAtomic ? load_state4(sp) : *(const float4*)sp;        \
            *(float4*)&xs[r][scol] = v;                                         \
        }                                                                       \
        __syncthreads();                                                        \
        _Pragma("unroll")                                                       \
        for (int b = 0; b < 32; ++b) {                                          \
            const float4 a0 = *(const float4*)&xs[b][kb];                       \
            const float4 a1 = *(const float4*)&xs[b][kb + 4];                   \
            acc[b] += a0.x * wc[0] + a0.y * wc[1]                               \
                    + a0.z * wc[2] + a0.w * wc[3]                               \
                    + a1.x * wc[4] + a1.y * wc[5]                               \
                    + a1.z * wc[6] + a1.w * wc[7];                              \
        }                                                                       \
    } while (0)

// One-time weight repack: Wpack[bid][jj][k_comb], k_comb 0..1023 = W_in column
// jbase+jj, 1024..2047 = W_h column. Writes fully coalesced float4; scattered
// reads are absorbed by L2 (block slice = 128 KB). ~64 MB total, ~30 us.
__global__ __launch_bounds__(512) void lnn_repack(
    const float* __restrict__ W_in, const float* __restrict__ W_h,
    float* __restrict__ Wpack)
{
    const int bid   = blockIdx.x;
    const int layer = bid >> 6;
    const int jbase = (bid & 63) << 4;
    const float* Win_l = W_in + (size_t)layer * D_ * H_;
    const float* Wh_l  = W_h  + (size_t)layer * H_ * H_;
    float* dst = Wpack + (size_t)bid * PACK_PER_BLK;
#pragma unroll 1
    for (int i = 0; i < 16; ++i) {
        const int f  = (i << 9) + threadIdx.x;   // float4 index 0..8191
        const int d  = f << 2;
        const int jj = d >> 11;
        const int k  = d & 2047;                 // k..k+3 stay in one half
        const float* s = (k < 1024) ? &Win_l[(size_t)k * H_ + jbase + jj]
                                    : &Wh_l[(size_t)(k - 1024) * H_ + jbase + jj];
        float4 v;
        v.x = s[0];
        v.y = s[(size_t)H_];
        v.z = s[(size_t)2 * H_];
        v.w = s[(size_t)3 * H_];
        *(float4*)&dst[d] = v;
    }
}

// Persistent kernel: 256 blocks (1/CU), 512 threads = 16 jj x 32 kslot.
// Everything except the weight-load addressing is byte-identical to R9
// (19.0 ms, VGPR=44, no spill). Hard lesson R10/R12/R13: 512-thread blocks
// cap at 128 VGPRs on this toolchain regardless of launch_bounds/attributes —
// keep live set small; never pin weights in registers or LDS.
template<bool PACKED>
__global__ __launch_bounds__(512, 2) void lnn_persist(
    const float* __restrict__ x,      // [B][T][D]
    const float* __restrict__ W_in,   // [L][D][H]
    const float* __restrict__ b_in,   // [L][H]
    const float* __restrict__ W_h,    // [L][H][H]
    const float* __restrict__ b_h,    // [L][H]
    const float* __restrict__ tau,    // [L][H]
    const float* __restrict__ Wpack,  // [256][PACK_PER_BLK] repacked weights
    float* __restrict__ buf0,         // [L][B][H] state, tick-parity 0
    float* __restrict__ buf1,         // [L][B][H] state, tick-parity 1
    unsigned int* __restrict__ count) // [NTICK] lockstep counters
{
    const int tid   = threadIdx.x;
    const int layer = blockIdx.x >> 6;
    const int jbase = (blockIdx.x & 63) << 4;
    const int jj    = tid & 15;       // col within slice
    const int kslot = tid >> 4;       // 0..31
    const int jg    = jbase + jj;
    const int kb    = kslot << 3;

    __shared__ __align__(16) float smem[SMEM_FLOATS];
    float (*xs)[256] = (float(*)[256])smem;

    const float* Wl_in = W_in + (size_t)layer * D_ * H_;
    const float* Wl_h  = W_h  + (size_t)layer * H_ * H_;
    const float* wbase = Wpack + ((size_t)blockIdx.x * PACK_PER_BLK) + ((size_t)jj << 11);

    const float bias = b_in[layer * H_ + jg] + b_h[layer * H_ + jg];
    const float tv   = tau[layer * H_ + jg];

    for (int tick = 0; tick < NTICK; ++tick) {
        if (tid == 0 && tick > 0)
            waitCount(&count[tick - 1], 256u);
        __syncthreads();   // all threads ordered after the wait

        const int t = tick - layer;
        if (t >= 0 && t < T_) {
            const float* rb   = (tick & 1) ? buf0 : buf1;   // state at t-1
            float*       wb   = (tick & 1) ? buf1 : buf0;   // state at t
            const float* hrow = rb + (size_t)layer * B_ * H_;

            const float* xsrc; size_t xstr;
            if (layer == 0) { xsrc = x + (size_t)t * D_;                  xstr = (size_t)T_ * D_; }
            else            { xsrc = rb + (size_t)(layer - 1) * B_ * H_;  xstr = H_; }

            float acc[32];
#pragma unroll
            for (int i = 0; i < 32; ++i) acc[i] = 0.f;

            // staging role: e = s4*512 + tid -> row e>>6, float4-col e&63
            const int srow = tid >> 6;
            const int scol = (tid & 63) << 2;

            TILE_BODY(0); TILE_BODY(1); TILE_BODY(2); TILE_BODY(3);
            TILE_BODY(4); TILE_BODY(5); TILE_BODY(6); TILE_BODY(7);

            // ---- two-phase k-reduction through padded LDS (proven R0/R7/R9) ----
            float* wl = wb + (size_t)layer * B_ * H_;
#pragma unroll 1
            for (int p = 0; p < 2; ++p) {
                __syncthreads();   // previous LDS use complete
#pragma unroll
                for (int c = 0; c < 16; ++c)
                    smem[tid * RP + c] = acc[p * 16 + c];
                __syncthreads();
                if (tid < 256) {
                    const int c = tid >> 4;            // 0..15
                    const int b = c + p * 16;
                    float s = 0.f;
#pragma unroll
                    for (int ks = 0; ks < 32; ++ks)
                        s += smem[(jj + (ks << 4)) * RP + c];
                    const float dx   = tanhf(s + bias);
                    const float hold = __hip_atomic_load(&hrow[(size_t)b * H_ + jg],
                                                         __ATOMIC_RELAXED, __HIP_MEMORY_SCOPE_AGENT);
                    const float hn   = hold + (dx - hold) / tv;
                    __hip_atomic_store(&wl[(size_t)b * H_ + jg], hn,
                                       __ATOMIC_RELAXED, __HIP_MEMORY_SCOPE_AGENT);
                }
            }
        }

        // __syncthreads() drains every wave's vmem ops (s_waitcnt vmcnt(0)
        // before s_barrier) -> all sc1 stores at MALL before the release-add.
        __syncthreads();
        if (tid == 0)
            __hip_atomic_fetch_add(&count[tick], 1u,
                                   __ATOMIC_RELEASE, __HIP_MEMORY_SCOPE_AGENT);
    }
}

// out[b][o] = sum_k h3[b][k] * W_out[k][o] + b_out[o]   (validated rounds 0-13)
__global__ __launch_bounds__(256) void lnn_out(
    const float* __restrict__ H3,     // [B][H]
    const float* __restrict__ W_out,  // [H][O]
    const float* __restrict__ b_out,  // [O]
    float* __restrict__ out)          // [B][O]
{
    const int gid = blockIdx.x * 256 + threadIdx.x;  // 64 blocks -> 16384 threads
    const int jj  = gid & 1023;
    const int b2  = gid >> 10;                       // 0..15 -> rows b2, b2+16
    float acc0 = b_out[jj];
    float acc1 = b_out[jj];
    for (int k = 0; k < H_; ++k) {
        const float w = W_out[k * H_ + jj];
        acc0 += H3[b2 * H_ + k]        * w;
        acc1 += H3[(b2 + 16) * H_ + k] * w;
    }
    out[b2 * H_ + jj]        = acc0;
    out[(b2 + 16) * H_ + jj] = acc1;
}

extern "C" void kernel_launch(void* const* d_in, const int* in_sizes, int n_in,
                              void* d_out, int out_size, void* d_ws, size_t ws_size,
                              hipStream_t stream) {
    const float* x     = (const float*)d_in[0];
    const float* W_in  = (const float*)d_in[1];
    const float* b_in  = (const float*)d_in[2];
    const float* W_h   = (const float*)d_in[3];
    const float* b_h   = (const float*)d_in[4];
    const float* tau   = (const float*)d_in[5];
    const float* W_out = (const float*)d_in[6];
    const float* b_out = (const float*)d_in[7];

    const size_t stateElems = (size_t)L_ * B_ * H_;          // 131072 floats
    const size_t packElems  = (size_t)256 * PACK_PER_BLK;    // 8388608 floats = 32 MB
    const size_t needPacked = (packElems + 2 * stateElems) * sizeof(float)
                            + NTICK * sizeof(unsigned int);
    const bool packed = (ws_size >= needPacked);

    float* Wpack;
    float* buf0;
    if (packed) { Wpack = (float*)d_ws;  buf0 = Wpack + packElems; }
    else        { Wpack = (float*)d_ws;  buf0 = (float*)d_ws; }     // fallback: R9 layout
    float* buf1 = buf0 + stateElems;
    unsigned int* count = (unsigned int*)(buf1 + stateElems);

    // zero state + lockstep counters (captured in graph -> reset every replay)
    (void)hipMemsetAsync(buf0, 0,
                         2 * stateElems * sizeof(float) + NTICK * sizeof(unsigned int), stream);

    if (packed) {
        lnn_repack<<<256, 512, 0, stream>>>(W_in, W_h, Wpack);
        lnn_persist<true><<<256, 512, 0, stream>>>(x, W_in, b_in, W_h, b_h, tau,
                                                   Wpack, buf0, buf1, count);
    } else {
        lnn_persist<false><<<256, 512, 0, stream>>>(x, W_in, b_in, W_h, b_h, tau,
                                                    Wpack, buf0, buf1, count);
    }

    // h3 at t=511 computed at tick 514 -> write parity 514&1 = 0 -> buf0.
    // Kernel boundary provides coherence for these plain loads.
    const float* H3 = buf0 + 3 * (B_ * H_);
    lnn_out<<<64, 256, 0, stream>>>(H3, W_out, b_out, (float*)d_out);
}

// Round 18
// 18202.031 us; speedup vs baseline: 11.0209x; 4.8065x over previous
//
#include <hip/hip_runtime.h>
#include <math.h>

#define B_ 32
#define T_ 512
#define D_ 1024
#define H_ 1024
#define L_ 4
#define NTICK (T_ + L_ - 1)    // 515
#define RP 17                  // reduce row pad (floats), proven R0/R7/R9
#define SMEM_FLOATS (512 * RP) // 34816 B; aliases staging tile xs[32][256]
#define PACK_PER_BLK 32768     // 16 cols x 2048 k floats = 128 KB per block

typedef unsigned long long u64;

// Cross-XCD state access: agent-scope relaxed atomics (sc1) hit the MALL
// coherence point directly. No fences anywhere -> XCD L2s never invalidated.
__device__ __forceinline__ float4 load_state4(const float* p) {
    u64 a = __hip_atomic_load((const u64*)p,       __ATOMIC_RELAXED, __HIP_MEMORY_SCOPE_AGENT);
    u64 b = __hip_atomic_load((const u64*)(p + 2), __ATOMIC_RELAXED, __HIP_MEMORY_SCOPE_AGENT);
    float4 v;
    v.x = __uint_as_float((unsigned)(a & 0xffffffffu));
    v.y = __uint_as_float((unsigned)(a >> 32));
    v.z = __uint_as_float((unsigned)(b & 0xffffffffu));
    v.w = __uint_as_float((unsigned)(b >> 32));
    return v;
}

// Relaxed spin + s_sleep throttle; short timeout + always-release => no hang.
__device__ __forceinline__ void waitCount(const unsigned int* p, unsigned int target) {
    int c = 0;
    while (__hip_atomic_load(p, __ATOMIC_RELAXED, __HIP_MEMORY_SCOPE_AGENT) < target) {
        __builtin_amdgcn_s_sleep(16);
        if (++c > 20000) return;   // ~4 ms/tick cap
    }
}

// One-time weight repack: Wpack[bid][jj][k_comb], k_comb 0..1023 = W_in column
// jbase+jj, 1024..2047 = W_h column. Writes fully coalesced float4; scattered
// reads absorbed by caches (block slice = 128 KB). 32 MB total, ~30 us.
__global__ __launch_bounds__(512) void lnn_repack(
    const float* __restrict__ W_in, const float* __restrict__ W_h,
    float* __restrict__ Wpack)
{
    const int bid   = blockIdx.x;
    const int layer = bid >> 6;
    const int jbase = (bid & 63) << 4;
    const float* Win_l = W_in + (size_t)layer * D_ * H_;
    const float* Wh_l  = W_h  + (size_t)layer * H_ * H_;
    float* dst = Wpack + (size_t)bid * PACK_PER_BLK;
#pragma unroll 1
    for (int i = 0; i < 16; ++i) {
        const int f  = (i << 9) + threadIdx.x;   // float4 index 0..8191
        const int d  = f << 2;
        const int jj = d >> 11;
        const int k  = d & 2047;                 // k..k+3 stay in one half
        const float* s = (k < 1024) ? &Win_l[(size_t)k * H_ + jbase + jj]
                                    : &Wh_l[(size_t)(k - 1024) * H_ + jbase + jj];
        float4 v;
        v.x = s[0];
        v.y = s[(size_t)H_];
        v.z = s[(size_t)2 * H_];
        v.w = s[(size_t)3 * H_];
        *(float4*)&dst[d] = v;
    }
}

// Persistent kernel: 256 blocks (1/CU), 512 threads = 16 jj x 32 kslot.
// Skeleton byte-identical to R9 (19.0 ms, VGPR=44, zero spill). Single
// variable vs R9: weights come from the packed per-block blob -> each tile's
// 8 weights are TWO CONTIGUOUS dwordx4 instead of 8 dwords strided 4 KB (R9
// counters: that strided stream moved at 1.0 TB/s = the whole 36.9 us tick).
//
// HARD RULE (R10/R13/R14 lesson): the tile loop must stay ROLLED
// (#pragma unroll 1). Full unroll -> compiler hoists 8 tiles' loads across
// barriers -> >128-reg live range -> scratch spill (WRITE_SIZE ~150 GB).
template<bool PACKED>
__global__ __launch_bounds__(512, 2) void lnn_persist(
    const float* __restrict__ x,      // [B][T][D]
    const float* __restrict__ W_in,   // [L][D][H]
    const float* __restrict__ b_in,   // [L][H]
    const float* __restrict__ W_h,    // [L][H][H]
    const float* __restrict__ b_h,    // [L][H]
    const float* __restrict__ tau,    // [L][H]
    const float* __restrict__ Wpack,  // [256][PACK_PER_BLK] repacked weights
    float* __restrict__ buf0,         // [L][B][H] state, tick-parity 0
    float* __restrict__ buf1,         // [L][B][H] state, tick-parity 1
    unsigned int* __restrict__ count) // [NTICK] lockstep counters
{
    const int tid   = threadIdx.x;
    const int layer = blockIdx.x >> 6;
    const int jbase = (blockIdx.x & 63) << 4;
    const int jj    = tid & 15;       // col within slice
    const int kslot = tid >> 4;       // 0..31
    const int jg    = jbase + jj;
    const int kb    = kslot << 3;

    __shared__ __align__(16) float smem[SMEM_FLOATS];
    float (*xs)[256] = (float(*)[256])smem;

    const float* Wl_in = W_in + (size_t)layer * D_ * H_;
    const float* Wl_h  = W_h  + (size_t)layer * H_ * H_;
    const float* wbase = Wpack + ((size_t)blockIdx.x * PACK_PER_BLK) + ((size_t)jj << 11);

    const float bias = b_in[layer * H_ + jg] + b_h[layer * H_ + jg];
    const float tv   = tau[layer * H_ + jg];

    for (int tick = 0; tick < NTICK; ++tick) {
        if (tid == 0 && tick > 0)
            waitCount(&count[tick - 1], 256u);
        __syncthreads();   // all threads ordered after the wait

        const int t = tick - layer;
        if (t >= 0 && t < T_) {
            const float* rb   = (tick & 1) ? buf0 : buf1;   // state at t-1
            float*       wb   = (tick & 1) ? buf1 : buf0;   // state at t
            const float* hrow = rb + (size_t)layer * B_ * H_;

            const float* xsrc; size_t xstr;
            if (layer == 0) { xsrc = x + (size_t)t * D_;                  xstr = (size_t)T_ * D_; }
            else            { xsrc = rb + (size_t)(layer - 1) * B_ * H_;  xstr = H_; }

            float acc[32];
#pragma unroll
            for (int i = 0; i < 32; ++i) acc[i] = 0.f;

            // staging role: e = s4*512 + tid -> row e>>6, float4-col e&63
            const int srow = tid >> 6;
            const int scol = (tid & 63) << 2;

#pragma unroll 1
            for (int tile = 0; tile < 8; ++tile) {
                const float* src = (tile < 4) ? xsrc : hrow;
                const size_t str = (tile < 4) ? xstr : (size_t)H_;
                const int    kof = (tile & 3) << 8;
                const bool   useAtomic = (tile >= 4) || (layer != 0);

                // this tile's 8 weights, issued before the barrier
                float wc[8];
                if constexpr (PACKED) {
                    const float4 wA = *(const float4*)&wbase[(tile << 8) + kb];
                    const float4 wB = *(const float4*)&wbase[(tile << 8) + kb + 4];
                    wc[0] = wA.x; wc[1] = wA.y; wc[2] = wA.z; wc[3] = wA.w;
                    wc[4] = wB.x; wc[5] = wB.y; wc[6] = wB.z; wc[7] = wB.w;
                } else {
                    const float* wp = ((tile < 4) ? Wl_in : Wl_h) + (size_t)(kof + kb) * H_ + jg;
#pragma unroll
                    for (int i = 0; i < 8; ++i) wc[i] = wp[(size_t)i * H_];
                }

                __syncthreads();   // previous tile's consumers done
#pragma unroll
                for (int s4 = 0; s4 < 4; ++s4) {
                    const int r = srow + (s4 << 3);
                    const float* sp = &src[(size_t)r * str + kof + scol];
                    float4 v = useAtomic ? load_state4(sp) : *(const float4*)sp;
                    *(float4*)&xs[r][scol] = v;
                }
                __syncthreads();

#pragma unroll
                for (int b = 0; b < 32; ++b) {
                    const float4 a0 = *(const float4*)&xs[b][kb];
                    const float4 a1 = *(const float4*)&xs[b][kb + 4];
                    acc[b] += a0.x * wc[0] + a0.y * wc[1]
                            + a0.z * wc[2] + a0.w * wc[3]
                            + a1.x * wc[4] + a1.y * wc[5]
                            + a1.z * wc[6] + a1.w * wc[7];
                }
            }

            // ---- two-phase k-reduction through padded LDS (proven R0/R7/R9) ----
            float* wl = wb + (size_t)layer * B_ * H_;
#pragma unroll 1
            for (int p = 0; p < 2; ++p) {
                __syncthreads();   // previous LDS use complete
#pragma unroll
                for (int c = 0; c < 16; ++c)
                    smem[tid * RP + c] = acc[p * 16 + c];
                __syncthreads();
                if (tid < 256) {
                    const int c = tid >> 4;            // 0..15
                    const int b = c + p * 16;
                    float s = 0.f;
#pragma unroll
                    for (int ks = 0; ks < 32; ++ks)
                        s += smem[(jj + (ks << 4)) * RP + c];
                    const float dx   = tanhf(s + bias);
                    const float hold = __hip_atomic_load(&hrow[(size_t)b * H_ + jg],
                                                         __ATOMIC_RELAXED, __HIP_MEMORY_SCOPE_AGENT);
                    const float hn   = hold + (dx - hold) / tv;
                    __hip_atomic_store(&wl[(size_t)b * H_ + jg], hn,
                                       __ATOMIC_RELAXED, __HIP_MEMORY_SCOPE_AGENT);
                }
            }
        }

        // __syncthreads() drains every wave's vmem ops (s_waitcnt vmcnt(0)
        // before s_barrier) -> all sc1 stores at MALL before the release-add.
        __syncthreads();
        if (tid == 0)
            __hip_atomic_fetch_add(&count[tick], 1u,
                                   __ATOMIC_RELEASE, __HIP_MEMORY_SCOPE_AGENT);
    }
}

// out[b][o] = sum_k h3[b][k] * W_out[k][o] + b_out[o]   (validated rounds 0-14)
__global__ __launch_bounds__(256) void lnn_out(
    const float* __restrict__ H3,     // [B][H]
    const float* __restrict__ W_out,  // [H][O]
    const float* __restrict__ b_out,  // [O]
    float* __restrict__ out)          // [B][O]
{
    const int gid = blockIdx.x * 256 + threadIdx.x;  // 64 blocks -> 16384 threads
    const int jj  = gid & 1023;
    const int b2  = gid >> 10;                       // 0..15 -> rows b2, b2+16
    float acc0 = b_out[jj];
    float acc1 = b_out[jj];
    for (int k = 0; k < H_; ++k) {
        const float w = W_out[k * H_ + jj];
        acc0 += H3[b2 * H_ + k]        * w;
        acc1 += H3[(b2 + 16) * H_ + k] * w;
    }
    out[b2 * H_ + jj]        = acc0;
    out[(b2 + 16) * H_ + jj] = acc1;
}

extern "C" void kernel_launch(void* const* d_in, const int* in_sizes, int n_in,
                              void* d_out, int out_size, void* d_ws, size_t ws_size,
                              hipStream_t stream) {
    const float* x     = (const float*)d_in[0];
    const float* W_in  = (const float*)d_in[1];
    const float* b_in  = (const float*)d_in[2];
    const float* W_h   = (const float*)d_in[3];
    const float* b_h   = (const float*)d_in[4];
    const float* tau   = (const float*)d_in[5];
    const float* W_out = (const float*)d_in[6];
    const float* b_out = (const float*)d_in[7];

    const size_t stateElems = (size_t)L_ * B_ * H_;          // 131072 floats
    const size_t packElems  = (size_t)256 * PACK_PER_BLK;    // 8388608 floats = 32 MB
    const size_t needPacked = (packElems + 2 * stateElems) * sizeof(float)
                            + NTICK * sizeof(unsigned int);
    const bool packed = (ws_size >= needPacked);

    float* Wpack = (float*)d_ws;
    float* buf0  = packed ? (Wpack + packElems) : (float*)d_ws;
    float* buf1  = buf0 + stateElems;
    unsigned int* count = (unsigned int*)(buf1 + stateElems);

    // zero state + lockstep counters (captured in graph -> reset every replay)
    (void)hipMemsetAsync(buf0, 0,
                         2 * stateElems * sizeof(float) + NTICK * sizeof(unsigned int), stream);

    if (packed) {
        lnn_repack<<<256, 512, 0, stream>>>(W_in, W_h, Wpack);
        lnn_persist<true><<<256, 512, 0, stream>>>(x, W_in, b_in, W_h, b_h, tau,
                                                   Wpack, buf0, buf1, count);
    } else {
        lnn_persist<false><<<256, 512, 0, stream>>>(x, W_in, b_in, W_h, b_h, tau,
                                                    Wpack, buf0, buf1, count);
    }

    // h3 at t=511 computed at tick 514 -> write parity 514&1 = 0 -> buf0.
    // Kernel boundary provides coherence for these plain loads.
    const float* H3 = buf0 + 3 * (B_ * H_);
    lnn_out<<<64, 256, 0, stream>>>(H3, W_out, b_out, (float*)d_out);
}

// Round 19
// 15544.368 us; speedup vs baseline: 12.9051x; 1.1710x over previous
//
#include <hip/hip_runtime.h>
#include <math.h>

#define B_ 32
#define T_ 512
#define D_ 1024
#define H_ 1024
#define L_ 4
#define NTICK (T_ + L_ - 1)    // 515
#define RPD 17                 // reduce row pad (floats)
#define PACK_PER_BLK 32768     // 16 cols x 2048 k floats = 128 KB per block

typedef unsigned long long u64;

// Cross-XCD state access: agent-scope relaxed atomics (sc1) hit the MALL
// coherence point directly. No fences anywhere -> XCD L2s never invalidated.
__device__ __forceinline__ float4 load_state4(const float* p) {
    u64 a = __hip_atomic_load((const u64*)p,       __ATOMIC_RELAXED, __HIP_MEMORY_SCOPE_AGENT);
    u64 b = __hip_atomic_load((const u64*)(p + 2), __ATOMIC_RELAXED, __HIP_MEMORY_SCOPE_AGENT);
    float4 v;
    v.x = __uint_as_float((unsigned)(a & 0xffffffffu));
    v.y = __uint_as_float((unsigned)(a >> 32));
    v.z = __uint_as_float((unsigned)(b & 0xffffffffu));
    v.w = __uint_as_float((unsigned)(b >> 32));
    return v;
}

// Relaxed spin + s_sleep throttle; short timeout + always-release => no hang.
__device__ __forceinline__ void waitCount(const unsigned int* p, unsigned int target) {
    int c = 0;
    while (__hip_atomic_load(p, __ATOMIC_RELAXED, __HIP_MEMORY_SCOPE_AGENT) < target) {
        __builtin_amdgcn_s_sleep(16);
        if (++c > 20000) return;   // ~4 ms/tick cap
    }
}

// One-time weight repack (unchanged from R18): Wpack[bid][col16][k2048].
__global__ __launch_bounds__(512) void lnn_repack(
    const float* __restrict__ W_in, const float* __restrict__ W_h,
    float* __restrict__ Wpack)
{
    const int bid   = blockIdx.x;
    const int layer = bid >> 6;
    const int jbase = (bid & 63) << 4;
    const float* Win_l = W_in + (size_t)layer * D_ * H_;
    const float* Wh_l  = W_h  + (size_t)layer * H_ * H_;
    float* dst = Wpack + (size_t)bid * PACK_PER_BLK;
#pragma unroll 1
    for (int i = 0; i < 16; ++i) {
        const int f  = (i << 9) + threadIdx.x;   // float4 index 0..8191
        const int d  = f << 2;
        const int jj = d >> 11;
        const int k  = d & 2047;                 // k..k+3 stay in one half
        const float* s = (k < 1024) ? &Win_l[(size_t)k * H_ + jbase + jj]
                                    : &Wh_l[(size_t)(k - 1024) * H_ + jbase + jj];
        float4 v;
        v.x = s[0];
        v.y = s[(size_t)H_];
        v.z = s[(size_t)2 * H_];
        v.w = s[(size_t)3 * H_];
        *(float4*)&dst[d] = v;
    }
}

// Reduce phase with LITERAL P (rule #20: acc indices must be compile-time).
// Threads dump acc[8P..8P+7] (float2 -> 16 floats); 128 threads sum the 64
// kslot partials of output (b = 8P + bo, jhat), apply tanh/tau, sc1-store.
#define REDUCE_PHASE(P)                                                         \
    do {                                                                        \
        __syncthreads();                                                        \
        _Pragma("unroll")                                                       \
        for (int q = 0; q < 8; ++q) {                                           \
            red[tid * RPD + (q << 1)]     = acc[((P) << 3) + q].x;              \
            red[tid * RPD + (q << 1) + 1] = acc[((P) << 3) + q].y;              \
        }                                                                       \
        __syncthreads();                                                        \
        if (tid < 128) {                                                        \
            const int bo   = tid >> 4;                                          \
            const int bh   = ((P) << 3) + bo;                                   \
            const int js   = (tid & 15) >> 1;                                   \
            const int comp = tid & 1;                                           \
            float s = 0.f;                                                      \
            _Pragma("unroll")                                                   \
            for (int ks = 0; ks < 64; ++ks)                                     \
                s += red[((ks << 3) + js) * RPD + (bo << 1) + comp];            \
            const float dx   = tanhf(s + bias);                                 \
            const float hold = __hip_atomic_load(&hrow[(size_t)bh * H_ + jr],   \
                                __ATOMIC_RELAXED, __HIP_MEMORY_SCOPE_AGENT);    \
            const float hn   = hold + (dx - hold) / tv;                         \
            __hip_atomic_store(&wl[(size_t)bh * H_ + jr], hn,                   \
                               __ATOMIC_RELAXED, __HIP_MEMORY_SCOPE_AGENT);     \
        }                                                                       \
    } while (0)

// Persistent kernel: 256 blocks (1/CU), 512 threads = 8 j-pairs x 64 kslots.
// R19 changes vs R18 (attacking the measured non-overlap terms):
//  (1) 2 output cols/thread: one ds_read_b128 feeds 8 FMAs (compute-DS halves
//      from ~20.5 to ~10 us/tick).
//  (2) double-buffered staging: next tile's loads issue into regs BEFORE this
//      tile's compute (MALL latency hides under it); ds_write + ONE barrier
//      per tile (was 2).
// HARD RULES kept: tile loop ROLLED (unroll 1) — full unroll spills past the
// immovable 128-VGPR cap (R10/R13/R14). wc loads issue BEFORE stg issues so
// the FMAs wait only on wc (counted vmcnt).
template<bool PACKED>
__global__ __launch_bounds__(512, 2) void lnn_persist(
    const float* __restrict__ x,      // [B][T][D]
    const float* __restrict__ W_in,   // [L][D][H]
    const float* __restrict__ b_in,   // [L][H]
    const float* __restrict__ W_h,    // [L][H][H]
    const float* __restrict__ b_h,    // [L][H]
    const float* __restrict__ tau,    // [L][H]
    const float* __restrict__ Wpack,  // [256][PACK_PER_BLK] repacked weights
    float* __restrict__ buf0,         // [L][B][H] state, tick-parity 0
    float* __restrict__ buf1,         // [L][B][H] state, tick-parity 1
    unsigned int* __restrict__ count) // [NTICK] lockstep counters
{
    const int tid   = threadIdx.x;
    const int layer = blockIdx.x >> 6;
    const int jbase = (blockIdx.x & 63) << 4;
    const int jp    = tid & 7;        // j-pair: cols jbase+2jp, +1
    const int kslot = tid >> 3;       // 0..63
    const int kb    = kslot << 2;     // k offset within 256-tile (floats)

    __shared__ __align__(16) float smem[16384];     // 64 KB: xs[2][32][256]
    float (*xs)[32][256] = (float(*)[32][256])smem;
    float* red = smem;                               // reduce aliases (34.8 KB)

    const float* Wl_in = W_in + (size_t)layer * D_ * H_;
    const float* Wl_h  = W_h  + (size_t)layer * H_ * H_;
    const float* wbaseA = Wpack + (size_t)blockIdx.x * PACK_PER_BLK
                        + ((size_t)(jp << 1) << 11);
    const float* wbaseB = wbaseA + 2048;
    const int jgA = jbase + (jp << 1);

    // reduce-reader per-thread constants (role: jhat = tid & 15)
    const int   jr   = jbase + (tid & 15);
    const float bias = b_in[layer * H_ + jr] + b_h[layer * H_ + jr];
    const float tv   = tau[layer * H_ + jr];

    // staging role: e = q*512 + tid -> row e>>6, float4-col e&63
    const int srow = tid >> 6;
    const int scol = (tid & 63) << 2;

    for (int tick = 0; tick < NTICK; ++tick) {
        if (tid == 0 && tick > 0)
            waitCount(&count[tick - 1], 256u);
        __syncthreads();   // all threads ordered after the wait

        const int t = tick - layer;
        if (t >= 0 && t < T_) {
            const float* rb   = (tick & 1) ? buf0 : buf1;   // state at t-1
            float*       wb   = (tick & 1) ? buf1 : buf0;   // state at t
            const float* hrow = rb + (size_t)layer * B_ * H_;
            float*       wl   = wb + (size_t)layer * B_ * H_;

            const float* xsrc; size_t xstr;
            if (layer == 0) { xsrc = x + (size_t)t * D_;                  xstr = (size_t)T_ * D_; }
            else            { xsrc = rb + (size_t)(layer - 1) * B_ * H_;  xstr = H_; }

            float2 acc[32];
#pragma unroll
            for (int i = 0; i < 32; ++i) acc[i] = make_float2(0.f, 0.f);

            // ---- prologue: stage tile 0 into xs[0] ----
            {
                const bool at0 = (layer != 0);
#pragma unroll
                for (int q = 0; q < 4; ++q) {
                    const int r = srow + (q << 3);
                    const float* sp = &xsrc[(size_t)r * xstr + scol];
                    float4 v = at0 ? load_state4(sp) : *(const float4*)sp;
                    *(float4*)&xs[0][r][scol] = v;
                }
            }
            __syncthreads();

#pragma unroll 1
            for (int tile = 0; tile < 8; ++tile) {
                const int cur = tile & 1;

                // (1) this tile's weights FIRST (FMAs wait only on these)
                float4 wA, wB;
                if constexpr (PACKED) {
                    wA = *(const float4*)&wbaseA[(tile << 8) + kb];
                    wB = *(const float4*)&wbaseB[(tile << 8) + kb];
                } else {
                    const int kof = (tile & 3) << 8;
                    const float* wp = ((tile < 4) ? Wl_in : Wl_h)
                                    + (size_t)(kof + kb) * H_ + jgA;
                    wA.x = wp[0];            wB.x = wp[1];
                    wA.y = wp[(size_t)H_];   wB.y = wp[(size_t)H_ + 1];
                    wA.z = wp[2*(size_t)H_]; wB.z = wp[2*(size_t)H_ + 1];
                    wA.w = wp[3*(size_t)H_]; wB.w = wp[3*(size_t)H_ + 1];
                }

                // (2) issue NEXT tile's staging loads (latency hides under (3))
                float4 stg[4];
                if (tile < 7) {
                    const int    nt   = tile + 1;
                    const float* nsrc = (nt < 4) ? xsrc : hrow;
                    const size_t nstr = (nt < 4) ? xstr : (size_t)H_;
                    const int    nkof = (nt & 3) << 8;
                    const bool   nat  = (nt >= 4) || (layer != 0);
#pragma unroll
                    for (int q = 0; q < 4; ++q) {
                        const int r = srow + (q << 3);
                        const float* sp = &nsrc[(size_t)r * nstr + nkof + scol];
                        stg[q] = nat ? load_state4(sp) : *(const float4*)sp;
                    }
                }

                // (3) compute this tile: 32 rows x {1 ds_read_b128 + 8 FMA}
#pragma unroll
                for (int b = 0; b < 32; ++b) {
                    const float4 a = *(const float4*)&xs[cur][b][kb];
                    acc[b].x += a.x * wA.x + a.y * wA.y + a.z * wA.z + a.w * wA.w;
                    acc[b].y += a.x * wB.x + a.y * wB.y + a.z * wB.z + a.w * wB.w;
                }

                // (4) write staged regs to the other buffer; ONE barrier/tile
                if (tile < 7) {
#pragma unroll
                    for (int q = 0; q < 4; ++q)
                        *(float4*)&xs[cur ^ 1][srow + (q << 3)][scol] = stg[q];
                }
                __syncthreads();
            }

            // ---- k-reduction: 4 phases, literal indices (rule #20) ----
            REDUCE_PHASE(0); REDUCE_PHASE(1); REDUCE_PHASE(2); REDUCE_PHASE(3);
        }

        // __syncthreads() drains every wave's vmem ops (s_waitcnt vmcnt(0)
        // before s_barrier) -> all sc1 stores at MALL before the release-add.
        __syncthreads();
        if (tid == 0)
            __hip_atomic_fetch_add(&count[tick], 1u,
                                   __ATOMIC_RELEASE, __HIP_MEMORY_SCOPE_AGENT);
    }
}

// out[b][o] = sum_k h3[b][k] * W_out[k][o] + b_out[o]   (validated rounds 0-18)
__global__ __launch_bounds__(256) void lnn_out(
    const float* __restrict__ H3,     // [B][H]
    const float* __restrict__ W_out,  // [H][O]
    const float* __restrict__ b_out,  // [O]
    float* __restrict__ out)          // [B][O]
{
    const int gid = blockIdx.x * 256 + threadIdx.x;  // 64 blocks -> 16384 threads
    const int jj  = gid & 1023;
    const int b2  = gid >> 10;                       // 0..15 -> rows b2, b2+16
    float acc0 = b_out[jj];
    float acc1 = b_out[jj];
    for (int k = 0; k < H_; ++k) {
        const float w = W_out[k * H_ + jj];
        acc0 += H3[b2 * H_ + k]        * w;
        acc1 += H3[(b2 + 16) * H_ + k] * w;
    }
    out[b2 * H_ + jj]        = acc0;
    out[(b2 + 16) * H_ + jj] = acc1;
}

extern "C" void kernel_launch(void* const* d_in, const int* in_sizes, int n_in,
                              void* d_out, int out_size, void* d_ws, size_t ws_size,
                              hipStream_t stream) {
    const float* x     = (const float*)d_in[0];
    const float* W_in  = (const float*)d_in[1];
    const float* b_in  = (const float*)d_in[2];
    const float* W_h   = (const float*)d_in[3];
    const float* b_h   = (const float*)d_in[4];
    const float* tau   = (const float*)d_in[5];
    const float* W_out = (const float*)d_in[6];
    const float* b_out = (const float*)d_in[7];

    const size_t stateElems = (size_t)L_ * B_ * H_;          // 131072 floats
    const size_t packElems  = (size_t)256 * PACK_PER_BLK;    // 32 MB
    const size_t needPacked = (packElems + 2 * stateElems) * sizeof(float)
                            + NTICK * sizeof(unsigned int);
    const bool packed = (ws_size >= needPacked);

    float* Wpack = (float*)d_ws;
    float* buf0  = packed ? (Wpack + packElems) : (float*)d_ws;
    float* buf1  = buf0 + stateElems;
    unsigned int* count = (unsigned int*)(buf1 + stateElems);

    // zero state + lockstep counters (captured in graph -> reset every replay)
    (void)hipMemsetAsync(buf0, 0,
                         2 * stateElems * sizeof(float) + NTICK * sizeof(unsigned int), stream);

    if (packed) {
        lnn_repack<<<256, 512, 0, stream>>>(W_in, W_h, Wpack);
        lnn_persist<true><<<256, 512, 0, stream>>>(x, W_in, b_in, W_h, b_h, tau,
                                                   Wpack, buf0, buf1, count);
    } else {
        lnn_persist<false><<<256, 512, 0, stream>>>(x, W_in, b_in, W_h, b_h, tau,
                                                    Wpack, buf0, buf1, count);
    }

    // h3 at t=511 computed at tick 514 -> write parity 514&1 = 0 -> buf0.
    // Kernel boundary provides coherence for these plain loads.
    const float* H3 = buf0 + 3 * (B_ * H_);
    lnn_out<<<64, 256, 0, stream>>>(H3, W_out, b_out, (float*)d_out);
}